// Round 1
// 747.629 us; speedup vs baseline: 1.0053x; 1.0053x over previous
//
#include <hip/hip_runtime.h>

#define BB 4
#define CC 128
#define HH 128
#define WW 128
#define HW (HH*WW)
#define CHW (CC*HW)
#define ND 81
#define CP 136      // c-stride (shorts) for uc/fgs: 272 B rows -> 16B aligned, 2-way-free b128 reads
#define UPITCH 40   // u-stride (shorts) for cu: 80 B rows = 5x16B -> b128-aligned
#define PP 32       // P tile u stride (shorts), 16B-aligned frag reads

typedef short s8v __attribute__((ext_vector_type(8)));   // 8 bf16 MFMA A/B frag
typedef short s4v __attribute__((ext_vector_type(4)));
typedef float f4v __attribute__((ext_vector_type(4)));   // MFMA C/D frag

__device__ __forceinline__ short f2bf(float x){          // RNE float->bf16 bits
  unsigned u = __float_as_uint(x);
  unsigned r = (u + 0x7FFFu + ((u >> 16) & 1u)) >> 16;
  return (short)r;
}
__device__ __forceinline__ float bf2f(short s){
  return __uint_as_float(((unsigned)(unsigned short)s) << 16);
}

// ---------------------------------------------------------------------------
// coef: [0..80]=target, [128..208]=vplus, [256..336]=alo, [384..464]=ahi,
//       [512]=step_length, [513]=reg_weight
// ---------------------------------------------------------------------------
__global__ void coef_kernel(const float* lw, const float* sw, const float* mw,
                            const float* lsl, const float* fr, float* coef){
  int d = threadIdx.x;
  if (d < ND){
    float dy = (float)(d / 9) - 4.0f;
    float dx = (float)(d % 9) - 4.0f;
    float dist = sqrtf(dy*dy + dx*dx) * 2.0f;
    float t = 0.f, v = 0.f, m = 0.f;
    for (int k = 0; k < 10; k++){
      float bd = dist - (float)k;
      float val = (k == 9) ? fminf(fmaxf(bd + 1.0f, 0.f), 1.f)
                           : fmaxf(1.0f - fabsf(bd), 0.f);
      t += val * lw[k]; v += val * sw[k]; m += val * mw[k];
    }
    float wm = 1.f / (1.f + expf(-m));
    coef[d] = t; coef[128+d] = v;
    coef[256+d] = (1.f - wm) * 0.5f;
    coef[384+d] = (1.f + wm) * 0.5f;
  }
  if (threadIdx.x == 0){
    coef[512] = expf(lsl[0]);
    float f = fr[0];
    coef[513] = fmaxf(f*f, 1e-10f) / (float)(CC*CC);
  }
}

// ---------------------------------------------------------------------------
// one-time convert: ref fp32 [b][c][h][w] ->
//   refU bf16 [b][h][c][w]  (u-contiguous, feeds cu staging)
//   refT bf16 [b][h][w][c]  (c-contiguous, feeds uc staging)
// Same RNE f2bf as the old in-loop conversion -> bit-identical staged values.
// ---------------------------------------------------------------------------
__global__ __launch_bounds__(256)
void cvt_kernel(const float* ref, short* refT, short* refU){
  __shared__ short T[128*130];
  int r = blockIdx.x, bb = blockIdx.y;
  int tid = threadIdx.x;
  const float* src = ref + (size_t)bb*CHW + (size_t)r*WW;
  short* uout = refU + (size_t)(bb*HH + r) * CC * WW;
  short* tout = refT + (size_t)(bb*HH + r) * WW * CC;
  #pragma unroll
  for (int k = 0; k < 16; k++){
    int q = tid + (k << 8);                 // 4096 float4 chunks
    int c = q >> 5, u0 = (q & 31) * 4;
    float4 v = *(const float4*)(src + (size_t)c*HW + u0);
    short h0 = f2bf(v.x), h1 = f2bf(v.y), h2 = f2bf(v.z), h3 = f2bf(v.w);
    s4v pk = {h0, h1, h2, h3};
    *(s4v*)&uout[(size_t)c*WW + u0] = pk;
    T[c*130 + u0 + 0] = h0; T[c*130 + u0 + 1] = h1;
    T[c*130 + u0 + 2] = h2; T[c*130 + u0 + 3] = h3;
  }
  __syncthreads();
  #pragma unroll
  for (int k = 0; k < 16; k++){
    int o = tid + (k << 8);
    int u = o >> 5, c0 = (o & 31) * 4;
    s4v pk = {T[(c0+0)*130 + u], T[(c0+1)*130 + u],
              T[(c0+2)*130 + u], T[(c0+3)*130 + u]};
    *(s4v*)&tout[(size_t)u*CC + c0] = pk;
  }
}

// ---------------------------------------------------------------------------
// kF: fully fused iteration for one (bb, 4-row y-band, 16-col x-tile).
// This round: XCD-chunked block swizzle (band-sharing tiles colocate on one
// L2), bf16 pre-transposed ref staging (PRE=1: 4x16B loads + 4x ds_write_b128
// per thread per stage), and a register prefetch pipeline (row rr+1 loads
// issued before barrier-B so latency hides under row rr's compute).
// LDS 29.2 KB map unchanged.
// ---------------------------------------------------------------------------
#define L_UC   0
#define L_FGS  8704
#define L_CU   8704
#define L_PM   18944
#define L_CF   26112
#define L_SG   27648
#define L_DEN  29184
#define L_NUM  29440
#define L_SA   29696
#define L_SZ   29952

template<int PRE>
__global__ __launch_bounds__(256, 4)
void kF(const float* f_in, const float* ref, const short* refT, const short* refU,
        const float* coef, float* f_out){
  __shared__ char smem[L_SZ];
  short* uc  = (short*)(smem + L_UC);    // [32 u][CP c]   (corr B-operand)
  short* cu  = (short*)(smem + L_CU);    // [128 c][UPITCH u] (corr_t B-operand, phase A)
  short* Pm  = (short*)(smem + L_PM);    // [4 wv][16 x][PP u]
  short* fgs = (short*)(smem + L_FGS);   // [64 px][CP c]  (fgrad, after phase A)
  float* s_t = (float*)(smem + L_CF);
  float* s_v = s_t + 96; float* s_al = s_t + 192; float* s_ah = s_t + 288;
  unsigned* sg = (unsigned*)(smem + L_SG);
  float* den = (float*)(smem + L_DEN);
  float* num = (float*)(smem + L_NUM);
  float* sa  = (float*)(smem + L_SA);

  int tid = threadIdx.x;
  int lane = tid & 63, wv = tid >> 6;
  int quad = lane >> 4, col = lane & 15;

  // XCD-chunked bijective swizzle: 1024 blocks, 8 XCDs -> XCD k owns virt
  // [128k,128k+128) = 16 consecutive y-bands of one batch (all x-tiles of a
  // band + its row-overlapping neighbors hit the same L2).
  int hwid = blockIdx.x + (blockIdx.y << 3) + (blockIdx.z << 8);
  int virt = ((hwid & 7) << 7) + (hwid >> 3);
  int bb = virt >> 8, y0 = ((virt >> 3) & 31) * 4, x0 = (virt & 7) * 16;

  int ub = x0 - 8;
  bool interior = (ub >= 0) && (ub + 32 <= WW);

  const float* fimg = f_in + (size_t)bb * CHW;
  const float* rimg = ref  + (size_t)bb * CHW;

  if (tid < ND){
    s_t[tid]  = coef[tid];       s_v[tid]  = coef[128+tid];
    s_al[tid] = coef[256+tid];   s_ah[tid] = coef[384+tid];
  }
  for (int e = tid; e < 384; e += 256) sg[e] = 0;
  if (tid < 64) den[tid] = 0.f;

  // ---- prefetch registers (PRE=1: bf16 chunks; PRE=0: raw fp32) ----
  s8v pT0, pT1, pU0, pU1;
  float4 pF0, pF1, pF2, pF3;

  auto loadRowA = [&](int r){
    if constexpr (PRE){
      const short* tb = refT + ((size_t)(bb*HH + r) * WW + ub) * CC;
      { int e = tid;       pT0 = *(const s8v*)(tb + (size_t)(e >> 4)*CC + ((e & 15) << 3)); }
      { int e = tid + 256; pT1 = *(const s8v*)(tb + (size_t)(e >> 4)*CC + ((e & 15) << 3)); }
      const short* ubp = refU + (size_t)(bb*HH + r) * CC * WW + ub;
      { int e = tid;       pU0 = *(const s8v*)(ubp + (size_t)(e >> 2)*WW + ((e & 3) << 3)); }
      { int e = tid + 256; pU1 = *(const s8v*)(ubp + (size_t)(e >> 2)*WW + ((e & 3) << 3)); }
    } else {
      const float* rb = rimg + (size_t)r * WW + ub;
      { int e = tid;       pF0 = *(const float4*)(rb + (size_t)(e >> 3)*HW + (e & 7)*4); }
      { int e = tid + 256; pF1 = *(const float4*)(rb + (size_t)(e >> 3)*HW + (e & 7)*4); }
      { int e = tid + 512; pF2 = *(const float4*)(rb + (size_t)(e >> 3)*HW + (e & 7)*4); }
      { int e = tid + 768; pF3 = *(const float4*)(rb + (size_t)(e >> 3)*HW + (e & 7)*4); }
    }
  };
  auto loadRowB = [&](int r){
    if constexpr (PRE){
      const short* tb = refT + ((size_t)(bb*HH + r) * WW + ub) * CC;
      { int e = tid;       pT0 = *(const s8v*)(tb + (size_t)(e >> 4)*CC + ((e & 15) << 3)); }
      { int e = tid + 256; pT1 = *(const s8v*)(tb + (size_t)(e >> 4)*CC + ((e & 15) << 3)); }
    } else {
      const float* rb = rimg + (size_t)r * WW + ub;
      { int e = tid;       pF0 = *(const float4*)(rb + (size_t)(e >> 3)*HW + (e & 7)*4); }
      { int e = tid + 256; pF1 = *(const float4*)(rb + (size_t)(e >> 3)*HW + (e & 7)*4); }
      { int e = tid + 512; pF2 = *(const float4*)(rb + (size_t)(e >> 3)*HW + (e & 7)*4); }
      { int e = tid + 768; pF3 = *(const float4*)(rb + (size_t)(e >> 3)*HW + (e & 7)*4); }
    }
  };
  auto writeRowA = [&](){
    if constexpr (PRE){
      { int e = tid;       *(s8v*)&uc[(e >> 4)*CP + ((e & 15) << 3)] = pT0; }
      { int e = tid + 256; *(s8v*)&uc[(e >> 4)*CP + ((e & 15) << 3)] = pT1; }
      { int e = tid;       *(s8v*)&cu[(e >> 2)*UPITCH + ((e & 3) << 3)] = pU0; }
      { int e = tid + 256; *(s8v*)&cu[(e >> 2)*UPITCH + ((e & 3) << 3)] = pU1; }
    } else {
      float4 vv[4] = {pF0, pF1, pF2, pF3};
      #pragma unroll
      for (int k = 0; k < 4; k++){
        int e4 = tid + (k << 8);
        int u4 = (e4 & 7) * 4, c = e4 >> 3;
        short h0 = f2bf(vv[k].x), h1 = f2bf(vv[k].y),
              h2 = f2bf(vv[k].z), h3 = f2bf(vv[k].w);
        uc[(u4+0)*CP + c] = h0; uc[(u4+1)*CP + c] = h1;
        uc[(u4+2)*CP + c] = h2; uc[(u4+3)*CP + c] = h3;
        s4v pk = {h0, h1, h2, h3};
        *(s4v*)&cu[c*UPITCH + u4] = pk;
      }
    }
  };
  auto writeRowB = [&](){
    if constexpr (PRE){
      { int e = tid;       *(s8v*)&uc[(e >> 4)*CP + ((e & 15) << 3)] = pT0; }
      { int e = tid + 256; *(s8v*)&uc[(e >> 4)*CP + ((e & 15) << 3)] = pT1; }
    } else {
      float4 vv[4] = {pF0, pF1, pF2, pF3};
      #pragma unroll
      for (int k = 0; k < 4; k++){
        int e4 = tid + (k << 8);
        int u4 = (e4 & 7) * 4, c = e4 >> 3;
        uc[(u4+0)*CP + c] = f2bf(vv[k].x); uc[(u4+1)*CP + c] = f2bf(vv[k].y);
        uc[(u4+2)*CP + c] = f2bf(vv[k].z); uc[(u4+3)*CP + c] = f2bf(vv[k].w);
      }
    }
  };
  auto edgeA = [&](int r){
    for (int e = tid; e < 4096; e += 256){
      int u = e & 31, c = e >> 5;
      int ua = ub + u;
      short h = 0;
      if (ua >= 0 && ua < WW){
        if constexpr (PRE) h = refT[((size_t)(bb*HH + r) * WW + ua) * CC + c];
        else h = f2bf(rimg[(size_t)c*HW + r*WW + ua]);
      }
      uc[u*CP + c] = h;
      cu[c*UPITCH + u] = h;
    }
  };
  auto edgeB = [&](int r){
    for (int e = tid; e < 4096; e += 256){
      int u = e & 31, c = e >> 5;
      int ua = ub + u;
      short h = 0;
      if (ua >= 0 && ua < WW){
        if constexpr (PRE) h = refT[((size_t)(bb*HH + r) * WW + ua) * CC + c];
        else h = f2bf(rimg[(size_t)c*HW + r*WW + ua]);
      }
      uc[u*CP + c] = h;
    }
  };

  // issue the first staging loads before anything else so they fly under
  // the A-frag build
  if (interior && y0 - 4 >= 0) loadRowA(y0 - 4);

  // ---- A-frags (f at row y0+wv, hi/lo split) straight from global ----
  int fy = y0 + wv;
  s8v a_hi[4], a_lo[4];
  #pragma unroll
  for (int kc = 0; kc < 4; kc++){
    short th[8], tl[8];
    #pragma unroll
    for (int j = 0; j < 8; j++){
      int c = kc*32 + quad*8 + j;
      float v = fimg[(size_t)c * HW + fy * WW + x0 + col];
      short h = f2bf(v);
      th[j] = h; tl[j] = f2bf(v - bf2f(h));
    }
    a_hi[kc] = *(const s8v*)th;
    a_lo[kc] = *(const s8v*)tl;
  }

  f4v D[8];
  #pragma unroll
  for (int i = 0; i < 8; i++) D[i] = (f4v)0.f;

  // =================== phase A: corr1 -> P -> corr_t ===================
  for (int rr = 0; rr < 12; rr++){
    int r = y0 + rr - 4;
    bool rv = (r >= 0) && (r < HH);
    __syncthreads();
    if (rv){
      if (interior) writeRowA();
      else edgeA(r);
    }
    if (interior && rr < 11){
      int rn = r + 1;
      if (rn >= 0 && rn < HH) loadRowA(rn);   // latency hides under compute
    }
    __syncthreads();
    int dy = rr - wv;
    if (rv && dy >= 0 && dy <= 8){
      // corr1: C[x,u] = sum_c (f_hi+f_lo)[x,c] * ref[c,u]
      f4v C0 = (f4v)0.f, C1 = (f4v)0.f;
      #pragma unroll
      for (int kc = 0; kc < 4; kc++){
        s8v b0 = *(const s8v*)&uc[col*CP      + kc*32 + quad*8];
        s8v b1 = *(const s8v*)&uc[(16+col)*CP + kc*32 + quad*8];
        C0 = __builtin_amdgcn_mfma_f32_16x16x32_bf16(a_hi[kc], b0, C0, 0,0,0);
        C0 = __builtin_amdgcn_mfma_f32_16x16x32_bf16(a_lo[kc], b0, C0, 0,0,0);
        C1 = __builtin_amdgcn_mfma_f32_16x16x32_bf16(a_hi[kc], b1, C1, 0,0,0);
        C1 = __builtin_amdgcn_mfma_f32_16x16x32_bf16(a_lo[kc], b1, C1, 0,0,0);
      }
      // scores -> signs + mapped -> P[x,u]
      #pragma unroll
      for (int nt = 0; nt < 2; nt++){
        f4v Cv = nt ? C1 : C0;
        #pragma unroll
        for (int reg = 0; reg < 4; reg++){
          int x  = quad*4 + reg;            // C/D row = (lane>>4)*4 + reg
          int up = nt*16 + col;             // C/D col = lane&15 (+tile)
          int dxm = up - x - 4;
          float m = 0.f;
          if (dxm >= 0 && dxm <= 8){
            float s = Cv[reg];
            int d = dy*9 + dxm;
            int px = wv*16 + x;
            float sgn = 0.f;
            if (s > 0.f){ sgn =  1.f; atomicOr(&sg[px*6     + (d>>5)], 1u << (d & 31)); }
            if (s < 0.f){ sgn = -1.f; atomicOr(&sg[px*6 + 3 + (d>>5)], 1u << (d & 31)); }
            float vp = s_v[d], al = s_al[d], ah = s_ah[d];
            float ga  = vp * (al * sgn + ah);
            float act = vp * (al * fabsf(s) + ah * s);
            m = ga * (act - vp * s_t[d]);
          }
          Pm[(wv*16 + x)*PP + up] = f2bf(m);
        }
      }
      __builtin_amdgcn_s_waitcnt(0);        // wave-local LDS handoff
      // corr_t: D[x,c] += sum_u P[x,u] * ref[u,c]
      s8v pa = *(const s8v*)&Pm[(wv*16 + col)*PP + quad*8];
      #pragma unroll
      for (int ct = 0; ct < 8; ct++){
        s8v bc = *(const s8v*)&cu[(ct*16 + col)*UPITCH + quad*8];
        D[ct] = __builtin_amdgcn_mfma_f32_16x16x32_bf16(pa, bc, D[ct], 0,0,0);
      }
    }
  }

  // ---- epilogue-1: fgs = bf16(D + rw*f) (overlays cu+Pm), then num ----
  float rw = coef[513];
  __syncthreads();
  #pragma unroll
  for (int ct = 0; ct < 8; ct++){
    #pragma unroll
    for (int reg = 0; reg < 4; reg++){
      int x = quad*4 + reg, c = ct*16 + col;
      float fv = fimg[(size_t)c * HW + fy * WW + x0 + x];
      fgs[(wv*16 + x)*CP + c] = f2bf(D[ct][reg] + rw * fv);
    }
  }
  __syncthreads();
  if (tid < 64){
    float s = 0.f;
    #pragma unroll
    for (int kc = 0; kc < 16; kc++){
      s8v v = *(const s8v*)&fgs[tid*CP + kc*8];
      #pragma unroll
      for (int j = 0; j < 8; j++){ float f = bf2f(v[j]); s += f*f; }
    }
    num[tid] = s;
  }

  // =================== phase B: corr(fgrad) -> den -> update ===================
  s8v ga_[4];
  #pragma unroll
  for (int kc = 0; kc < 4; kc++)
    ga_[kc] = *(const s8v*)&fgs[(wv*16 + col)*CP + kc*32 + quad*8];

  if (interior && y0 - 4 >= 0) loadRowB(y0 - 4);

  for (int rr = 0; rr < 12; rr++){
    int r = y0 + rr - 4;
    bool rv = (r >= 0) && (r < HH);
    __syncthreads();
    if (rv){
      if (interior) writeRowB();
      else edgeB(r);
    }
    if (interior && rr < 11){
      int rn = r + 1;
      if (rn >= 0 && rn < HH) loadRowB(rn);
    }
    __syncthreads();
    int dy = rr - wv;
    if (rv && dy >= 0 && dy <= 8){
      f4v C0 = (f4v)0.f, C1 = (f4v)0.f;
      #pragma unroll
      for (int kc = 0; kc < 4; kc++){
        s8v b0 = *(const s8v*)&uc[col*CP      + kc*32 + quad*8];
        s8v b1 = *(const s8v*)&uc[(16+col)*CP + kc*32 + quad*8];
        C0 = __builtin_amdgcn_mfma_f32_16x16x32_bf16(ga_[kc], b0, C0, 0,0,0);
        C1 = __builtin_amdgcn_mfma_f32_16x16x32_bf16(ga_[kc], b1, C1, 0,0,0);
      }
      #pragma unroll
      for (int nt = 0; nt < 2; nt++){
        f4v Cv = nt ? C1 : C0;
        #pragma unroll
        for (int reg = 0; reg < 4; reg++){
          int x  = quad*4 + reg;
          int up = nt*16 + col;
          int dxm = up - x - 4;
          if (dxm >= 0 && dxm <= 8){
            int d = dy*9 + dxm;
            int px = wv*16 + x;
            float sgn = ((sg[px*6 + (d>>5)] >> (d&31)) & 1u) ? 1.f
                      : (((sg[px*6 + 3 + (d>>5)] >> (d&31)) & 1u) ? -1.f : 0.f);
            float ga = s_v[d] * (s_al[d]*sgn + s_ah[d]);
            float t  = Cv[reg];
            float sgv = ga * t;
            atomicAdd(&den[px], sgv*sgv);
          }
        }
      }
    }
  }

  __syncthreads();
  if (tid < 64){
    float step = coef[512];
    float alpha = num[tid] / fmaxf(den[tid] + rw*num[tid], 1e-8f);
    sa[tid] = step * alpha;
  }
  __syncthreads();

  // ---- update: f_out = f - step*alpha*fgrad (coalesced) ----
  float* oimg = f_out + (size_t)bb * CHW;
  for (int e = tid; e < 8192; e += 256){
    int x = e & 15, y = (e >> 4) & 3, c = e >> 6;
    size_t gi = (size_t)c * HW + (y0 + y) * WW + x0 + x;
    float v = fimg[gi] - sa[y*16 + x] * bf2f(fgs[(y*16 + x)*CP + c]);
    oimg[gi] = v;
  }
}

// ---------------------------------------------------------------------------
extern "C" void kernel_launch(void* const* d_in, const int* in_sizes, int n_in,
                              void* d_out, int out_size, void* d_ws, size_t ws_size,
                              hipStream_t stream) {
  const float* filter_map = (const float*)d_in[0];
  const float* ref        = (const float*)d_in[1];
  const float* label_w    = (const float*)d_in[2];
  const float* spatial_w  = (const float*)d_in[3];
  const float* mask_w     = (const float*)d_in[4];
  const float* lsl        = (const float*)d_in[5];
  const float* freg       = (const float*)d_in[6];

  float* coef = (float*)d_ws;      // 1024 floats (plus pad to 64 KB)
  float* fbuf = (float*)d_out;     // evolving filter lives in d_out (fp32)

  // bf16 pre-transposed ref copies in workspace (guarded by ws_size)
  short* refT = (short*)((char*)d_ws + 65536);
  short* refU = refT + (size_t)BB * CHW;
  size_t need = 65536 + 2 * (size_t)BB * CHW * sizeof(short);
  bool pre = (ws_size >= need);

  coef_kernel<<<dim3(1), dim3(128), 0, stream>>>(label_w, spatial_w, mask_w, lsl, freg, coef);
  if (pre)
    cvt_kernel<<<dim3(HH, BB), dim3(256), 0, stream>>>(ref, refT, refU);

  dim3 grid(8, 32, BB);   // 16-col x-tiles, 4-row y-bands, batch
  for (int it = 0; it < 3; it++){
    const float* fsrc = (it == 0) ? filter_map : (const float*)fbuf;
    if (pre) kF<1><<<grid, 256, 0, stream>>>(fsrc, ref, refT, refU, coef, fbuf);
    else     kF<0><<<grid, 256, 0, stream>>>(fsrc, ref, refT, refU, coef, fbuf);
  }
}

// Round 2
// 351.697 us; speedup vs baseline: 2.1371x; 2.1258x over previous
//
#include <hip/hip_runtime.h>

#define BB 4
#define CC 128
#define HH 128
#define WW 128
#define HW (HH*WW)
#define CHW (CC*HW)
#define ND 81
#define CP 136      // c-stride (shorts) for uc/fgs: 272 B rows -> 16B aligned, 2-way-free b128 reads
#define UPITCH 40   // u-stride (shorts) for cu: 80 B rows = 5x16B -> b128-aligned
#define PP 32       // P tile u stride (shorts), 16B-aligned frag reads
#define SP 88       // sgn byte stride per px row

typedef short s8v __attribute__((ext_vector_type(8)));   // 8 bf16 MFMA A/B frag
typedef short s4v __attribute__((ext_vector_type(4)));
typedef float f4v __attribute__((ext_vector_type(4)));   // MFMA C/D frag

__device__ __forceinline__ short f2bf(float x){          // RNE float->bf16 bits
  unsigned u = __float_as_uint(x);
  unsigned r = (u + 0x7FFFu + ((u >> 16) & 1u)) >> 16;
  return (short)r;
}
__device__ __forceinline__ float bf2f(short s){
  return __uint_as_float(((unsigned)(unsigned short)s) << 16);
}

// ---------------------------------------------------------------------------
// coef: [0..80]=target, [128..208]=vplus, [256..336]=alo, [384..464]=ahi,
//       [512]=step_length, [513]=reg_weight
// ---------------------------------------------------------------------------
__global__ void coef_kernel(const float* lw, const float* sw, const float* mw,
                            const float* lsl, const float* fr, float* coef){
  int d = threadIdx.x;
  if (d < ND){
    float dy = (float)(d / 9) - 4.0f;
    float dx = (float)(d % 9) - 4.0f;
    float dist = sqrtf(dy*dy + dx*dx) * 2.0f;
    float t = 0.f, v = 0.f, m = 0.f;
    for (int k = 0; k < 10; k++){
      float bd = dist - (float)k;
      float val = (k == 9) ? fminf(fmaxf(bd + 1.0f, 0.f), 1.f)
                           : fmaxf(1.0f - fabsf(bd), 0.f);
      t += val * lw[k]; v += val * sw[k]; m += val * mw[k];
    }
    float wm = 1.f / (1.f + expf(-m));
    coef[d] = t; coef[128+d] = v;
    coef[256+d] = (1.f - wm) * 0.5f;
    coef[384+d] = (1.f + wm) * 0.5f;
  }
  if (threadIdx.x == 0){
    coef[512] = expf(lsl[0]);
    float f = fr[0];
    coef[513] = fmaxf(f*f, 1e-10f) / (float)(CC*CC);
  }
}

// ---------------------------------------------------------------------------
// one-time convert: ref fp32 [b][c][h][w] ->
//   refU bf16 [b][h][c][w]  (u-contiguous, feeds cu staging)
//   refT bf16 [b][h][w][c]  (c-contiguous, feeds uc staging)
// ---------------------------------------------------------------------------
__global__ __launch_bounds__(256)
void cvt_kernel(const float* ref, short* refT, short* refU){
  __shared__ short T[128*130];
  int r = blockIdx.x, bb = blockIdx.y;
  int tid = threadIdx.x;
  const float* src = ref + (size_t)bb*CHW + (size_t)r*WW;
  short* uout = refU + (size_t)(bb*HH + r) * CC * WW;
  short* tout = refT + (size_t)(bb*HH + r) * WW * CC;
  #pragma unroll
  for (int k = 0; k < 16; k++){
    int q = tid + (k << 8);                 // 4096 float4 chunks
    int c = q >> 5, u0 = (q & 31) * 4;
    float4 v = *(const float4*)(src + (size_t)c*HW + u0);
    short h0 = f2bf(v.x), h1 = f2bf(v.y), h2 = f2bf(v.z), h3 = f2bf(v.w);
    s4v pk = {h0, h1, h2, h3};
    *(s4v*)&uout[(size_t)c*WW + u0] = pk;
    T[c*130 + u0 + 0] = h0; T[c*130 + u0 + 1] = h1;
    T[c*130 + u0 + 2] = h2; T[c*130 + u0 + 3] = h3;
  }
  __syncthreads();
  #pragma unroll
  for (int k = 0; k < 16; k++){
    int o = tid + (k << 8);
    int u = o >> 5, c0 = (o & 31) * 4;
    s4v pk = {T[(c0+0)*130 + u], T[(c0+1)*130 + u],
              T[(c0+2)*130 + u], T[(c0+3)*130 + u]};
    *(s4v*)&tout[(size_t)u*CC + c0] = pk;
  }
}

// ---------------------------------------------------------------------------
// kF: this round —
//  * loads for row r+1 issued AFTER barrier 2 (start of compute) so the
//    compiler's vmcnt(0)-drain at the NEXT barrier is covered by compute
//  * no LDS atomics: sign -> unique-writer byte array; den -> register
//    accumulation + __shfl_xor reduce
//  * edge tiles use the same predicated vector staging as interior
//    (chunks are uniformly valid/invalid since ub = +-8 mod 16)
// LDS 34.0 KB: uc 8704 | fgs 17408 (A-overlay: cu 10240 + Pm 4096) |
//              coefs 1536 | sgn 5632 | den/num/sa 768
// ---------------------------------------------------------------------------
#define L_UC   0
#define L_FGS  8704
#define L_CU   8704
#define L_PM   18944
#define L_CF   26112
#define L_SGN  27648
#define L_DEN  33280
#define L_NUM  33536
#define L_SA   33792
#define L_SZ   34048

template<int PRE>
__global__ __launch_bounds__(256, 4)
void kF(const float* f_in, const float* ref, const short* refT, const short* refU,
        const float* coef, float* f_out){
  __shared__ char smem[L_SZ];
  short* uc  = (short*)(smem + L_UC);    // [32 u][CP c]   (corr B-operand)
  short* cu  = (short*)(smem + L_CU);    // [128 c][UPITCH u] (corr_t B-operand, phase A)
  short* Pm  = (short*)(smem + L_PM);    // [4 wv][16 x][PP u]
  short* fgs = (short*)(smem + L_FGS);   // [64 px][CP c]  (fgrad, after phase A)
  float* s_t = (float*)(smem + L_CF);
  float* s_v = s_t + 96; float* s_al = s_t + 192; float* s_ah = s_t + 288;
  signed char* sgn = (signed char*)(smem + L_SGN);   // [64 px][SP d] unique writer
  float* den = (float*)(smem + L_DEN);
  float* num = (float*)(smem + L_NUM);
  float* sa  = (float*)(smem + L_SA);

  int tid = threadIdx.x;
  int lane = tid & 63, wv = tid >> 6;
  int quad = lane >> 4, col = lane & 15;

  // XCD-chunked bijective swizzle (1024 blocks, 8 XCDs)
  int hwid = blockIdx.x + (blockIdx.y << 3) + (blockIdx.z << 8);
  int virt = ((hwid & 7) << 7) + (hwid >> 3);
  int bb = virt >> 8, y0 = ((virt >> 3) & 31) * 4, x0 = (virt & 7) * 16;

  int ub = x0 - 8;

  const float* fimg = f_in + (size_t)bb * CHW;
  const float* rimg = ref  + (size_t)bb * CHW;

  if (tid < ND){
    s_t[tid]  = coef[tid];       s_v[tid]  = coef[128+tid];
    s_al[tid] = coef[256+tid];   s_ah[tid] = coef[384+tid];
  }

  // ---- prefetch registers (PRE=1: bf16 chunks; PRE=0: raw fp32) ----
  s8v pT0, pT1, pU0, pU1;
  float4 pF0, pF1, pF2, pF3;

  auto loadT = [&](int r){
    if constexpr (PRE){
      const short* tb = refT + (size_t)(bb*HH + r) * WW * CC;
      { int e = tid;       int ua = ub + (e >> 4);
        pT0 = (ua >= 0 && ua < WW)
              ? *(const s8v*)(tb + (size_t)ua*CC + ((e & 15) << 3)) : (s8v)(short)0; }
      { int e = tid + 256; int ua = ub + (e >> 4);
        pT1 = (ua >= 0 && ua < WW)
              ? *(const s8v*)(tb + (size_t)ua*CC + ((e & 15) << 3)) : (s8v)(short)0; }
    } else {
      const float* rb = rimg + (size_t)r * WW;
      float4 z; z.x = z.y = z.z = z.w = 0.f;
      { int e = tid;       int ua = ub + (e & 7)*4;
        pF0 = (ua >= 0 && ua + 4 <= WW) ? *(const float4*)(rb + (size_t)(e >> 3)*HW + ua) : z; }
      { int e = tid + 256; int ua = ub + (e & 7)*4;
        pF1 = (ua >= 0 && ua + 4 <= WW) ? *(const float4*)(rb + (size_t)(e >> 3)*HW + ua) : z; }
      { int e = tid + 512; int ua = ub + (e & 7)*4;
        pF2 = (ua >= 0 && ua + 4 <= WW) ? *(const float4*)(rb + (size_t)(e >> 3)*HW + ua) : z; }
      { int e = tid + 768; int ua = ub + (e & 7)*4;
        pF3 = (ua >= 0 && ua + 4 <= WW) ? *(const float4*)(rb + (size_t)(e >> 3)*HW + ua) : z; }
    }
  };
  auto loadU = [&](int r){
    if constexpr (PRE){
      const short* ubp = refU + (size_t)(bb*HH + r) * CC * WW;
      { int e = tid;       int ua = ub + ((e & 3) << 3);
        pU0 = (ua >= 0 && ua + 8 <= WW)
              ? *(const s8v*)(ubp + (size_t)(e >> 2)*WW + ua) : (s8v)(short)0; }
      { int e = tid + 256; int ua = ub + ((e & 3) << 3);
        pU1 = (ua >= 0 && ua + 8 <= WW)
              ? *(const s8v*)(ubp + (size_t)(e >> 2)*WW + ua) : (s8v)(short)0; }
    }
  };
  auto writeRowA = [&](){
    if constexpr (PRE){
      { int e = tid;       *(s8v*)&uc[(e >> 4)*CP + ((e & 15) << 3)] = pT0; }
      { int e = tid + 256; *(s8v*)&uc[(e >> 4)*CP + ((e & 15) << 3)] = pT1; }
      { int e = tid;       *(s8v*)&cu[(e >> 2)*UPITCH + ((e & 3) << 3)] = pU0; }
      { int e = tid + 256; *(s8v*)&cu[(e >> 2)*UPITCH + ((e & 3) << 3)] = pU1; }
    } else {
      float4 vv[4] = {pF0, pF1, pF2, pF3};
      #pragma unroll
      for (int k = 0; k < 4; k++){
        int e4 = tid + (k << 8);
        int u4 = (e4 & 7) * 4, c = e4 >> 3;
        short h0 = f2bf(vv[k].x), h1 = f2bf(vv[k].y),
              h2 = f2bf(vv[k].z), h3 = f2bf(vv[k].w);
        uc[(u4+0)*CP + c] = h0; uc[(u4+1)*CP + c] = h1;
        uc[(u4+2)*CP + c] = h2; uc[(u4+3)*CP + c] = h3;
        s4v pk = {h0, h1, h2, h3};
        *(s4v*)&cu[c*UPITCH + u4] = pk;
      }
    }
  };
  auto writeRowB = [&](){
    if constexpr (PRE){
      { int e = tid;       *(s8v*)&uc[(e >> 4)*CP + ((e & 15) << 3)] = pT0; }
      { int e = tid + 256; *(s8v*)&uc[(e >> 4)*CP + ((e & 15) << 3)] = pT1; }
    } else {
      float4 vv[4] = {pF0, pF1, pF2, pF3};
      #pragma unroll
      for (int k = 0; k < 4; k++){
        int e4 = tid + (k << 8);
        int u4 = (e4 & 7) * 4, c = e4 >> 3;
        uc[(u4+0)*CP + c] = f2bf(vv[k].x); uc[(u4+1)*CP + c] = f2bf(vv[k].y);
        uc[(u4+2)*CP + c] = f2bf(vv[k].z); uc[(u4+3)*CP + c] = f2bf(vv[k].w);
      }
    }
  };

  // prologue: loads for rr=0 (row y0-4), in flight under the A-frag build
  if (y0 - 4 >= 0){ loadT(y0 - 4); loadU(y0 - 4); }

  // ---- A-frags (f at row y0+wv, hi/lo split) straight from global ----
  int fy = y0 + wv;
  s8v a_hi[4], a_lo[4];
  #pragma unroll
  for (int kc = 0; kc < 4; kc++){
    short th[8], tl[8];
    #pragma unroll
    for (int j = 0; j < 8; j++){
      int c = kc*32 + quad*8 + j;
      float v = fimg[(size_t)c * HW + fy * WW + x0 + col];
      short h = f2bf(v);
      th[j] = h; tl[j] = f2bf(v - bf2f(h));
    }
    a_hi[kc] = *(const s8v*)th;
    a_lo[kc] = *(const s8v*)tl;
  }

  f4v D[8];
  #pragma unroll
  for (int i = 0; i < 8; i++) D[i] = (f4v)0.f;

  // =================== phase A: corr1 -> P -> corr_t ===================
  for (int rr = 0; rr < 12; rr++){
    int r = y0 + rr - 4;
    bool rv = (r >= 0) && (r < HH);
    __syncthreads();
    if (rv) writeRowA();
    __syncthreads();
    // issue next row's loads NOW: the vmcnt(0)-drain at the next barrier
    // is then covered by the compute below
    if (rr < 11){
      int rn = r + 1;
      if (rn >= 0 && rn < HH){ loadT(rn); loadU(rn); }
    }
    int dy = rr - wv;
    if (rv && dy >= 0 && dy <= 8){
      // corr1: C[x,u] = sum_c (f_hi+f_lo)[x,c] * ref[c,u]
      f4v C0 = (f4v)0.f, C1 = (f4v)0.f;
      #pragma unroll
      for (int kc = 0; kc < 4; kc++){
        s8v b0 = *(const s8v*)&uc[col*CP      + kc*32 + quad*8];
        s8v b1 = *(const s8v*)&uc[(16+col)*CP + kc*32 + quad*8];
        C0 = __builtin_amdgcn_mfma_f32_16x16x32_bf16(a_hi[kc], b0, C0, 0,0,0);
        C0 = __builtin_amdgcn_mfma_f32_16x16x32_bf16(a_lo[kc], b0, C0, 0,0,0);
        C1 = __builtin_amdgcn_mfma_f32_16x16x32_bf16(a_hi[kc], b1, C1, 0,0,0);
        C1 = __builtin_amdgcn_mfma_f32_16x16x32_bf16(a_lo[kc], b1, C1, 0,0,0);
      }
      // scores -> sign bytes (unique writer, no atomics) + mapped -> P[x,u]
      #pragma unroll
      for (int nt = 0; nt < 2; nt++){
        f4v Cv = nt ? C1 : C0;
        #pragma unroll
        for (int reg = 0; reg < 4; reg++){
          int x  = quad*4 + reg;            // C/D row = (lane>>4)*4 + reg
          int up = nt*16 + col;             // C/D col = lane&15 (+tile)
          int dxm = up - x - 4;
          float m = 0.f;
          if (dxm >= 0 && dxm <= 8){
            float s = Cv[reg];
            int d = dy*9 + dxm;
            int px = wv*16 + x;
            signed char sc = (s > 0.f) ? (signed char)1
                           : ((s < 0.f) ? (signed char)-1 : (signed char)0);
            sgn[px*SP + d] = sc;
            float sgf = (float)sc;
            float vp = s_v[d], al = s_al[d], ah = s_ah[d];
            float ga  = vp * (al * sgf + ah);
            float act = vp * (al * fabsf(s) + ah * s);
            m = ga * (act - vp * s_t[d]);
          }
          Pm[(wv*16 + x)*PP + up] = f2bf(m);
        }
      }
      // wave-local LDS handoff: wait LDS only (keep prefetch loads in flight)
      asm volatile("s_waitcnt lgkmcnt(0)" ::: "memory");
      __builtin_amdgcn_sched_barrier(0);
      // corr_t: D[x,c] += sum_u P[x,u] * ref[u,c]
      s8v pa = *(const s8v*)&Pm[(wv*16 + col)*PP + quad*8];
      #pragma unroll
      for (int ct = 0; ct < 8; ct++){
        s8v bc = *(const s8v*)&cu[(ct*16 + col)*UPITCH + quad*8];
        D[ct] = __builtin_amdgcn_mfma_f32_16x16x32_bf16(pa, bc, D[ct], 0,0,0);
      }
    }
  }

  // phase-B prologue loads fly under the epilogue work
  if (y0 - 4 >= 0) loadT(y0 - 4);

  // ---- epilogue-1: fgs = bf16(D + rw*f) (overlays cu+Pm), then num ----
  float rw = coef[513];
  __syncthreads();
  #pragma unroll
  for (int ct = 0; ct < 8; ct++){
    #pragma unroll
    for (int reg = 0; reg < 4; reg++){
      int x = quad*4 + reg, c = ct*16 + col;
      float fv = fimg[(size_t)c * HW + fy * WW + x0 + x];
      fgs[(wv*16 + x)*CP + c] = f2bf(D[ct][reg] + rw * fv);
    }
  }
  __syncthreads();
  if (tid < 64){
    float s = 0.f;
    #pragma unroll
    for (int kc = 0; kc < 16; kc++){
      s8v v = *(const s8v*)&fgs[tid*CP + kc*8];
      #pragma unroll
      for (int j = 0; j < 8; j++){ float f = bf2f(v[j]); s += f*f; }
    }
    num[tid] = s;
  }

  // =================== phase B: corr(fgrad) -> den -> update ===================
  s8v ga_[4];
  #pragma unroll
  for (int kc = 0; kc < 4; kc++)
    ga_[kc] = *(const s8v*)&fgs[(wv*16 + col)*CP + kc*32 + quad*8];

  float dacc[4] = {0.f, 0.f, 0.f, 0.f};    // per-thread den partials (by reg)

  for (int rr = 0; rr < 12; rr++){
    int r = y0 + rr - 4;
    bool rv = (r >= 0) && (r < HH);
    __syncthreads();
    if (rv) writeRowB();
    __syncthreads();
    if (rr < 11){
      int rn = r + 1;
      if (rn >= 0 && rn < HH) loadT(rn);
    }
    int dy = rr - wv;
    if (rv && dy >= 0 && dy <= 8){
      f4v C0 = (f4v)0.f, C1 = (f4v)0.f;
      #pragma unroll
      for (int kc = 0; kc < 4; kc++){
        s8v b0 = *(const s8v*)&uc[col*CP      + kc*32 + quad*8];
        s8v b1 = *(const s8v*)&uc[(16+col)*CP + kc*32 + quad*8];
        C0 = __builtin_amdgcn_mfma_f32_16x16x32_bf16(ga_[kc], b0, C0, 0,0,0);
        C1 = __builtin_amdgcn_mfma_f32_16x16x32_bf16(ga_[kc], b1, C1, 0,0,0);
      }
      #pragma unroll
      for (int nt = 0; nt < 2; nt++){
        f4v Cv = nt ? C1 : C0;
        #pragma unroll
        for (int reg = 0; reg < 4; reg++){
          int x  = quad*4 + reg;
          int up = nt*16 + col;
          int dxm = up - x - 4;
          if (dxm >= 0 && dxm <= 8){
            int d = dy*9 + dxm;
            int px = wv*16 + x;
            float sgf = (float)sgn[px*SP + d];
            float ga = s_v[d] * (s_al[d]*sgf + s_ah[d]);
            float t  = Cv[reg];
            float sgv = ga * t;
            dacc[reg] += sgv*sgv;
          }
        }
      }
    }
  }

  // den: reduce partials across the 16 col-lanes of each quad (no atomics)
  #pragma unroll
  for (int reg = 0; reg < 4; reg++){
    float v = dacc[reg];
    v += __shfl_xor(v, 1);
    v += __shfl_xor(v, 2);
    v += __shfl_xor(v, 4);
    v += __shfl_xor(v, 8);
    if (col == 0) den[wv*16 + quad*4 + reg] = v;
  }

  __syncthreads();
  if (tid < 64){
    float step = coef[512];
    float alpha = num[tid] / fmaxf(den[tid] + rw*num[tid], 1e-8f);
    sa[tid] = step * alpha;
  }
  __syncthreads();

  // ---- update: f_out = f - step*alpha*fgrad (coalesced) ----
  float* oimg = f_out + (size_t)bb * CHW;
  for (int e = tid; e < 8192; e += 256){
    int x = e & 15, y = (e >> 4) & 3, c = e >> 6;
    size_t gi = (size_t)c * HW + (y0 + y) * WW + x0 + x;
    float v = fimg[gi] - sa[y*16 + x] * bf2f(fgs[(y*16 + x)*CP + c]);
    oimg[gi] = v;
  }
}

// ---------------------------------------------------------------------------
extern "C" void kernel_launch(void* const* d_in, const int* in_sizes, int n_in,
                              void* d_out, int out_size, void* d_ws, size_t ws_size,
                              hipStream_t stream) {
  const float* filter_map = (const float*)d_in[0];
  const float* ref        = (const float*)d_in[1];
  const float* label_w    = (const float*)d_in[2];
  const float* spatial_w  = (const float*)d_in[3];
  const float* mask_w     = (const float*)d_in[4];
  const float* lsl        = (const float*)d_in[5];
  const float* freg       = (const float*)d_in[6];

  float* coef = (float*)d_ws;      // 1024 floats (plus pad to 64 KB)
  float* fbuf = (float*)d_out;     // evolving filter lives in d_out (fp32)

  // bf16 pre-transposed ref copies in workspace (guarded by ws_size)
  short* refT = (short*)((char*)d_ws + 65536);
  short* refU = refT + (size_t)BB * CHW;
  size_t need = 65536 + 2 * (size_t)BB * CHW * sizeof(short);
  bool pre = (ws_size >= need);

  coef_kernel<<<dim3(1), dim3(128), 0, stream>>>(label_w, spatial_w, mask_w, lsl, freg, coef);
  if (pre)
    cvt_kernel<<<dim3(HH, BB), dim3(256), 0, stream>>>(ref, refT, refU);

  dim3 grid(8, 32, BB);   // 16-col x-tiles, 4-row y-bands, batch
  for (int it = 0; it < 3; it++){
    const float* fsrc = (it == 0) ? filter_map : (const float*)fbuf;
    if (pre) kF<1><<<grid, 256, 0, stream>>>(fsrc, ref, refT, refU, coef, fbuf);
    else     kF<0><<<grid, 256, 0, stream>>>(fsrc, ref, refT, refU, coef, fbuf);
  }
}